// Round 8
// baseline (948.356 us; speedup 1.0000x reference)
//
#include <hip/hip_runtime.h>
#include <hip/hip_fp16.h>

#define NN 100000
#define HD 64
#define NB ((NN + 255) >> 8)   // 391 dst-buckets of 256 nodes

__global__ void deg_kernel(const int* __restrict__ dst, int* __restrict__ deg, int E) {
    int e = blockIdx.x * blockDim.x + threadIdx.x;
    if (e < E) atomicAdd(&deg[dst[e]], 1);
}

__global__ void dinv_kernel(const int* __restrict__ deg, float* __restrict__ dinv, int n) {
    int v = blockIdx.x * blockDim.x + threadIdx.x;
    if (v < n) dinv[v] = rsqrtf((float)deg[v] + 1.0f);  // +1 = self loop
}

// ---- 3-kernel exclusive scan over deg -> row_ptr ----
__global__ void scanA_kernel(const int* __restrict__ deg, int* __restrict__ bsum, int n) {
    __shared__ int sm[256];
    int i = blockIdx.x * 256 + threadIdx.x;
    sm[threadIdx.x] = (i < n) ? deg[i] : 0;
    __syncthreads();
    for (int off = 128; off > 0; off >>= 1) {
        if (threadIdx.x < off) sm[threadIdx.x] += sm[threadIdx.x + off];
        __syncthreads();
    }
    if (threadIdx.x == 0) bsum[blockIdx.x] = sm[0];
}

__global__ void scanB_kernel(int* __restrict__ bsum, int* __restrict__ row_ptr, int nb, int n) {
    __shared__ int sm[512];
    int t = threadIdx.x;
    int v = (t < nb) ? bsum[t] : 0;
    sm[t] = v;
    __syncthreads();
    for (int off = 1; off < 512; off <<= 1) {
        int u = (t >= off) ? sm[t - off] : 0;
        __syncthreads();
        sm[t] += u;
        __syncthreads();
    }
    if (t < nb) bsum[t] = sm[t] - v;  // exclusive block offset
    if (t == 511) row_ptr[n] = sm[511];
}

__global__ void scanC_kernel(const int* __restrict__ deg, const int* __restrict__ bsum,
                             int* __restrict__ row_ptr, int n) {
    __shared__ int sm[256];
    int i = blockIdx.x * 256 + threadIdx.x;
    int v = (i < n) ? deg[i] : 0;
    sm[threadIdx.x] = v;
    __syncthreads();
    for (int off = 1; off < 256; off <<= 1) {
        int u = (threadIdx.x >= off) ? sm[threadIdx.x - off] : 0;
        __syncthreads();
        sm[threadIdx.x] += u;
        __syncthreads();
    }
    if (i < n) row_ptr[i] = sm[threadIdx.x] - v + bsum[blockIdx.x];
}

// bucket cursors: bcur[b] = row_ptr[b*256] (bucketing preserves CSR order)
__global__ void bcur_init_kernel(const int* __restrict__ row_ptr, int* __restrict__ bcur) {
    int i = blockIdx.x * blockDim.x + threadIdx.x;
    if (i < NB) bcur[i] = row_ptr[i << 8];
}

// pass 1: scatter (dst,src) pairs into per-bucket frontiers (8B stores, frontier-local)
__global__ void p1_kernel(const int* __restrict__ src, const int* __restrict__ dst,
                          int* __restrict__ bcur, int2* __restrict__ ebuf, int E) {
    int e = blockIdx.x * blockDim.x + threadIdx.x;
    if (e < E) {
        int d = dst[e], s = src[e];
        int pos = atomicAdd(&bcur[d >> 8], 1);
        ebuf[pos] = make_int2(d, s);
    }
}

// pass 2: one block per bucket; LDS cursors; scatter src into block-local csr slice
__global__ __launch_bounds__(256) void p2_kernel(const int2* __restrict__ ebuf,
                                                 const int* __restrict__ row_ptr,
                                                 int* __restrict__ csr_src, int n) {
    __shared__ int cur[256];
    int b = blockIdx.x;
    int node0 = b << 8;
    int nend = min(n, node0 + 256);
    int t = threadIdx.x;
    if (node0 + t < nend) cur[t] = row_ptr[node0 + t];
    __syncthreads();
    int beg = row_ptr[node0];
    int end = row_ptr[nend];
    for (int i = beg + t; i < end; i += 256) {
        int2 p = ebuf[i];
        int pos = atomicAdd(&cur[p.x - node0], 1);
        csr_src[pos] = p.y;
    }
}

// H(fp16) = (X @ W) * dinv[row] — 64x64 tile/block, 4x4 micro-tile/thread
__global__ __launch_bounds__(256) void matmul64_kernel(const float* __restrict__ X,
                                                       const float* __restrict__ W,
                                                       const float* __restrict__ dinv,
                                                       float2* __restrict__ H, int n) {
    __shared__ float Wl[64 * 64];      // [k][c], float4-aligned
    __shared__ float Xs[64 * 65];      // [r][k], padded
    int tid = threadIdx.x;
    int row0 = blockIdx.x * 64;
    const float4* W4 = (const float4*)W;
    float4* Wl4 = (float4*)Wl;
#pragma unroll
    for (int i = 0; i < 4; ++i) Wl4[tid + 256 * i] = W4[tid + 256 * i];
#pragma unroll
    for (int i = 0; i < 4; ++i) {
        int l = tid + 256 * i;          // 1024 float4s = 64 rows x 16
        int r = l >> 4, k0 = (l & 15) * 4;
        int row = row0 + r;
        float4 xv = (row < n) ? ((const float4*)X)[(size_t)row * 16 + (l & 15)]
                              : make_float4(0.f, 0.f, 0.f, 0.f);
        Xs[r * 65 + k0 + 0] = xv.x;
        Xs[r * 65 + k0 + 1] = xv.y;
        Xs[r * 65 + k0 + 2] = xv.z;
        Xs[r * 65 + k0 + 3] = xv.w;
    }
    __syncthreads();
    int tx = tid & 15, ty = tid >> 4;   // cols c0=4*tx, rows r0=4*ty
    float acc[4][4] = {};
    const float4* Wlr4 = (const float4*)Wl;
#pragma unroll 4
    for (int k = 0; k < 64; ++k) {
        float4 b = Wlr4[k * 16 + tx];
        float a0 = Xs[(ty * 4 + 0) * 65 + k];
        float a1 = Xs[(ty * 4 + 1) * 65 + k];
        float a2 = Xs[(ty * 4 + 2) * 65 + k];
        float a3 = Xs[(ty * 4 + 3) * 65 + k];
        acc[0][0] += a0 * b.x; acc[0][1] += a0 * b.y; acc[0][2] += a0 * b.z; acc[0][3] += a0 * b.w;
        acc[1][0] += a1 * b.x; acc[1][1] += a1 * b.y; acc[1][2] += a1 * b.z; acc[1][3] += a1 * b.w;
        acc[2][0] += a2 * b.x; acc[2][1] += a2 * b.y; acc[2][2] += a2 * b.z; acc[2][3] += a2 * b.w;
        acc[3][0] += a3 * b.x; acc[3][1] += a3 * b.y; acc[3][2] += a3 * b.z; acc[3][3] += a3 * b.w;
    }
#pragma unroll
    for (int j = 0; j < 4; ++j) {
        int row = row0 + ty * 4 + j;
        if (row < n) {
            float dn = dinv[row];
            __half2 p01 = __float22half2_rn(make_float2(acc[j][0] * dn, acc[j][1] * dn));
            __half2 p23 = __float22half2_rn(make_float2(acc[j][2] * dn, acc[j][3] * dn));
            float2 st;
            st.x = *reinterpret_cast<float*>(&p01);
            st.y = *reinterpret_cast<float*>(&p23);
            H[(size_t)row * 16 + tx] = st;
        }
    }
}

#define UNPACK_ACC(A, RAW) do {                                              \
    __half2 _h01 = *reinterpret_cast<__half2*>(&(RAW).x);                    \
    __half2 _h23 = *reinterpret_cast<__half2*>(&(RAW).y);                    \
    float2 _f01 = __half22float2(_h01);                                      \
    float2 _f23 = __half22float2(_h23);                                      \
    (A).x += _f01.x; (A).y += _f01.y; (A).z += _f23.x; (A).w += _f23.y;      \
} while (0)

// one QUARTER-wave (16 lanes) per node; lane c4 owns channels 4*c4..4*c4+3 (fp16 x4 = 8B).
// Inner edge loop unrolled 8/4/1-wide so up to 8 gathers are in flight per quarter.
__global__ void agg_kernel(const float2* __restrict__ h2, const int* __restrict__ row_ptr,
                           const int* __restrict__ csr_src, const float* __restrict__ dinv,
                           const float* __restrict__ b, const float* __restrict__ xprev,
                           float* __restrict__ xout, float* __restrict__ outp,
                           const float* __restrict__ Wc, const float* __restrict__ bc,
                           int n, int residual, int project) {
    int lane = threadIdx.x & 63;
    int q = lane >> 4, c4 = lane & 15;
    int wid = (blockIdx.x * blockDim.x + threadIdx.x) >> 6;
    int node = wid * 4 + q;
    bool active = node < n;
    int nc = active ? node : 0;
    int beg = row_ptr[nc], end = row_ptr[nc + 1];
    int cnt = end - beg;
    float4 acc = make_float4(0.f, 0.f, 0.f, 0.f);
    {
        float2 raw = h2[(size_t)nc * 16 + c4];  // self loop (pre-scaled by dinv[src])
        UNPACK_ACC(acc, raw);
    }
    int base = q * 16;
    for (int k = 0; k < cnt; k += 16) {
        int p = beg + k + c4;
        int sv = (p < end) ? csr_src[p] : 0;
        int m = min(16, cnt - k);
        int i = 0;
        for (; i + 8 <= m; i += 8) {
            int s0 = __shfl(sv, base + i + 0);
            int s1 = __shfl(sv, base + i + 1);
            int s2 = __shfl(sv, base + i + 2);
            int s3 = __shfl(sv, base + i + 3);
            int s4 = __shfl(sv, base + i + 4);
            int s5 = __shfl(sv, base + i + 5);
            int s6 = __shfl(sv, base + i + 6);
            int s7 = __shfl(sv, base + i + 7);
            float2 v0 = h2[(size_t)s0 * 16 + c4];
            float2 v1 = h2[(size_t)s1 * 16 + c4];
            float2 v2 = h2[(size_t)s2 * 16 + c4];
            float2 v3 = h2[(size_t)s3 * 16 + c4];
            float2 v4 = h2[(size_t)s4 * 16 + c4];
            float2 v5 = h2[(size_t)s5 * 16 + c4];
            float2 v6 = h2[(size_t)s6 * 16 + c4];
            float2 v7 = h2[(size_t)s7 * 16 + c4];
            UNPACK_ACC(acc, v0); UNPACK_ACC(acc, v1); UNPACK_ACC(acc, v2); UNPACK_ACC(acc, v3);
            UNPACK_ACC(acc, v4); UNPACK_ACC(acc, v5); UNPACK_ACC(acc, v6); UNPACK_ACC(acc, v7);
        }
        for (; i + 4 <= m; i += 4) {
            int s0 = __shfl(sv, base + i + 0);
            int s1 = __shfl(sv, base + i + 1);
            int s2 = __shfl(sv, base + i + 2);
            int s3 = __shfl(sv, base + i + 3);
            float2 v0 = h2[(size_t)s0 * 16 + c4];
            float2 v1 = h2[(size_t)s1 * 16 + c4];
            float2 v2 = h2[(size_t)s2 * 16 + c4];
            float2 v3 = h2[(size_t)s3 * 16 + c4];
            UNPACK_ACC(acc, v0); UNPACK_ACC(acc, v1); UNPACK_ACC(acc, v2); UNPACK_ACC(acc, v3);
        }
        for (; i < m; ++i) {
            int s = __shfl(sv, base + i);
            float2 hv = h2[(size_t)s * 16 + c4];
            UNPACK_ACC(acc, hv);
        }
    }
    if (active) {
        float dn = dinv[node];
        float4 bb = ((const float4*)b)[c4];
        float4 v;
        v.x = acc.x * dn + bb.x; v.y = acc.y * dn + bb.y;
        v.z = acc.z * dn + bb.z; v.w = acc.w * dn + bb.w;
        if (residual) {
            float4 r = ((const float4*)xprev)[(size_t)node * 16 + c4];
            v.x += r.x; v.y += r.y; v.z += r.z; v.w += r.w;
        }
        v.x = fmaxf(v.x, 0.f); v.y = fmaxf(v.y, 0.f);
        v.z = fmaxf(v.z, 0.f); v.w = fmaxf(v.w, 0.f);
        if (!project) {
            ((float4*)xout)[(size_t)node * 16 + c4] = v;
        } else {
            int cb = c4 * 4;
#pragma unroll
            for (int j = 0; j < 3; ++j) {
                float p = v.x * Wc[(cb + 0) * 3 + j] + v.y * Wc[(cb + 1) * 3 + j] +
                          v.z * Wc[(cb + 2) * 3 + j] + v.w * Wc[(cb + 3) * 3 + j];
                p += __shfl_down(p, 8);
                p += __shfl_down(p, 4);
                p += __shfl_down(p, 2);
                p += __shfl_down(p, 1);
                if (c4 == 0) outp[node * 3 + j] = p + bc[j];
            }
        }
    }
}

extern "C" void kernel_launch(void* const* d_in, const int* in_sizes, int n_in,
                              void* d_out, int out_size, void* d_ws, size_t ws_size,
                              hipStream_t stream) {
    const float* x  = (const float*)d_in[0];
    const int*   ei = (const int*)d_in[1];
    const float* Ws = (const float*)d_in[2];
    const float* bs = (const float*)d_in[3];
    const float* Wc = (const float*)d_in[4];
    const float* bc = (const float*)d_in[5];
    float* out = (float*)d_out;

    int E = in_sizes[1] / 2;
    const int* src = ei;
    const int* dst = ei + E;
    int nb = (NN + 255) / 256;

    char* wsb = (char*)d_ws;
    size_t off = 0;
    int*   deg     = (int*)(wsb + off); off += 100352 * 4;
    float* dinv    = (float*)(wsb + off); off += 100352 * 4;
    int*   row_ptr = (int*)(wsb + off); off += 100608 * 4;
    int*   bcur    = (int*)(wsb + off); off += 512 * 4;
    int*   bsum    = (int*)(wsb + off); off += 512 * 4;
    int*   csr_src = (int*)(wsb + off); off += ((size_t)E + 256) * 4;
    int2*  ebuf    = (int2*)(wsb + off); off += (size_t)E * 8;           // bucketed pairs
    float2* h      = (float2*)(wsb + off); off += (size_t)NN * HD * 2;   // fp16 h
    float* xa      = (float*)(wsb + off); off += (size_t)NN * HD * 4;
    float* xb      = (float*)(wsb + off); off += (size_t)NN * HD * 4;

    // graph build
    hipMemsetAsync(deg, 0, NN * sizeof(int), stream);
    deg_kernel<<<(E + 255) / 256, 256, 0, stream>>>(dst, deg, E);
    dinv_kernel<<<(NN + 255) / 256, 256, 0, stream>>>(deg, dinv, NN);
    scanA_kernel<<<nb, 256, 0, stream>>>(deg, bsum, NN);
    scanB_kernel<<<1, 512, 0, stream>>>(bsum, row_ptr, nb, NN);
    scanC_kernel<<<nb, 256, 0, stream>>>(deg, bsum, row_ptr, NN);
    bcur_init_kernel<<<(NB + 255) / 256, 256, 0, stream>>>(row_ptr, bcur);
    p1_kernel<<<(E + 255) / 256, 256, 0, stream>>>(src, dst, bcur, ebuf, E);
    p2_kernel<<<NB, 256, 0, stream>>>(ebuf, row_ptr, csr_src, NN);

    // layers (ping-pong xa/xb); layer 3 fuses projection into agg epilogue
    const float* xin = x;
    float* bufs[2] = {xa, xb};
    int agg_blocks = ((NN + 3) / 4 * 64 + 255) / 256;  // 4 nodes per wave
    for (int l = 0; l < 4; ++l) {
        float* xout = bufs[l & 1];
        matmul64_kernel<<<(NN + 63) / 64, 256, 0, stream>>>(
            xin, Ws + (size_t)l * HD * HD, dinv, h, NN);
        agg_kernel<<<agg_blocks, 256, 0, stream>>>(
            h, row_ptr, csr_src, dinv, bs + l * HD, xin, xout,
            out, Wc, bc, NN, l > 0, l == 3);
        xin = xout;
    }
}

// Round 9
// 408.756 us; speedup vs baseline: 2.3201x; 2.3201x over previous
//
#include <hip/hip_runtime.h>
#include <hip/hip_fp16.h>

#define NN 100000
#define HD 64
#define NB ((NN + 255) >> 8)   // 391 dst-buckets of 256 nodes
#define P1_CHUNK 8192

__global__ void deg_kernel(const int* __restrict__ dst, int* __restrict__ deg, int E) {
    int e = blockIdx.x * blockDim.x + threadIdx.x;
    if (e < E) atomicAdd(&deg[dst[e]], 1);
}

__global__ void dinv_kernel(const int* __restrict__ deg, float* __restrict__ dinv, int n) {
    int v = blockIdx.x * blockDim.x + threadIdx.x;
    if (v < n) dinv[v] = rsqrtf((float)deg[v] + 1.0f);  // +1 = self loop
}

// ---- 3-kernel exclusive scan over deg -> row_ptr ----
__global__ void scanA_kernel(const int* __restrict__ deg, int* __restrict__ bsum, int n) {
    __shared__ int sm[256];
    int i = blockIdx.x * 256 + threadIdx.x;
    sm[threadIdx.x] = (i < n) ? deg[i] : 0;
    __syncthreads();
    for (int off = 128; off > 0; off >>= 1) {
        if (threadIdx.x < off) sm[threadIdx.x] += sm[threadIdx.x + off];
        __syncthreads();
    }
    if (threadIdx.x == 0) bsum[blockIdx.x] = sm[0];
}

__global__ void scanB_kernel(int* __restrict__ bsum, int* __restrict__ row_ptr, int nb, int n) {
    __shared__ int sm[512];
    int t = threadIdx.x;
    int v = (t < nb) ? bsum[t] : 0;
    sm[t] = v;
    __syncthreads();
    for (int off = 1; off < 512; off <<= 1) {
        int u = (t >= off) ? sm[t - off] : 0;
        __syncthreads();
        sm[t] += u;
        __syncthreads();
    }
    if (t < nb) bsum[t] = sm[t] - v;  // exclusive block offset
    if (t == 511) row_ptr[n] = sm[511];
}

__global__ void scanC_kernel(const int* __restrict__ deg, const int* __restrict__ bsum,
                             int* __restrict__ row_ptr, int n) {
    __shared__ int sm[256];
    int i = blockIdx.x * 256 + threadIdx.x;
    int v = (i < n) ? deg[i] : 0;
    sm[threadIdx.x] = v;
    __syncthreads();
    for (int off = 1; off < 256; off <<= 1) {
        int u = (threadIdx.x >= off) ? sm[threadIdx.x - off] : 0;
        __syncthreads();
        sm[threadIdx.x] += u;
        __syncthreads();
    }
    if (i < n) row_ptr[i] = sm[threadIdx.x] - v + bsum[blockIdx.x];
}

// bucket cursors: bcur[b] = row_ptr[b*256] (range-bucketing preserves CSR block order)
__global__ void bcur_init_kernel(const int* __restrict__ row_ptr, int* __restrict__ bcur) {
    int i = blockIdx.x * blockDim.x + threadIdx.x;
    if (i < NB) bcur[i] = row_ptr[i << 8];
}

// pass 1 (chunked): LDS histogram -> one global atomic per (block,bucket) -> LDS-cursor scatter
__global__ __launch_bounds__(256) void p1_kernel(const int* __restrict__ src,
                                                 const int* __restrict__ dst,
                                                 int* __restrict__ bcur,
                                                 int2* __restrict__ ebuf, int E) {
    __shared__ int hist[NB];
    __shared__ int cur[NB];
    int t = threadIdx.x;
    int e0 = blockIdx.x * P1_CHUNK;
    int count = min(P1_CHUNK, E - e0);
    for (int b = t; b < NB; b += 256) hist[b] = 0;
    __syncthreads();
    for (int i = t; i < count; i += 256) atomicAdd(&hist[dst[e0 + i] >> 8], 1);
    __syncthreads();
    for (int b = t; b < NB; b += 256) {
        int c = hist[b];
        cur[b] = c ? atomicAdd(&bcur[b], c) : 0;
    }
    __syncthreads();
    for (int i = t; i < count; i += 256) {
        int d = dst[e0 + i], s = src[e0 + i];
        int pos = atomicAdd(&cur[d >> 8], 1);
        ebuf[pos] = make_int2(d, s);
    }
}

// pass 2: one block per bucket; LDS per-node cursors; writes stay in a ~64KB local window
__global__ __launch_bounds__(256) void p2_kernel(const int2* __restrict__ ebuf,
                                                 const int* __restrict__ row_ptr,
                                                 int* __restrict__ csr_src, int n) {
    __shared__ int cur[256];
    int b = blockIdx.x;
    int node0 = b << 8;
    int nend = min(n, node0 + 256);
    int t = threadIdx.x;
    if (node0 + t < nend) cur[t] = row_ptr[node0 + t];
    __syncthreads();
    int beg = row_ptr[node0];
    int end = row_ptr[nend];
    for (int i = beg + t; i < end; i += 256) {
        int2 p = ebuf[i];
        int pos = atomicAdd(&cur[p.x - node0], 1);
        csr_src[pos] = p.y;
    }
}

// H(fp16) = (X @ W) * dinv[row] — 64x64 tile/block, 4x4 micro-tile/thread
__global__ __launch_bounds__(256) void matmul64_kernel(const float* __restrict__ X,
                                                       const float* __restrict__ W,
                                                       const float* __restrict__ dinv,
                                                       float2* __restrict__ H, int n) {
    __shared__ float Wl[64 * 64];      // [k][c], float4-aligned
    __shared__ float Xs[64 * 65];      // [r][k], padded
    int tid = threadIdx.x;
    int row0 = blockIdx.x * 64;
    const float4* W4 = (const float4*)W;
    float4* Wl4 = (float4*)Wl;
#pragma unroll
    for (int i = 0; i < 4; ++i) Wl4[tid + 256 * i] = W4[tid + 256 * i];
#pragma unroll
    for (int i = 0; i < 4; ++i) {
        int l = tid + 256 * i;          // 1024 float4s = 64 rows x 16
        int r = l >> 4, k0 = (l & 15) * 4;
        int row = row0 + r;
        float4 xv = (row < n) ? ((const float4*)X)[(size_t)row * 16 + (l & 15)]
                              : make_float4(0.f, 0.f, 0.f, 0.f);
        Xs[r * 65 + k0 + 0] = xv.x;
        Xs[r * 65 + k0 + 1] = xv.y;
        Xs[r * 65 + k0 + 2] = xv.z;
        Xs[r * 65 + k0 + 3] = xv.w;
    }
    __syncthreads();
    int tx = tid & 15, ty = tid >> 4;   // cols c0=4*tx, rows r0=4*ty
    float acc[4][4] = {};
    const float4* Wlr4 = (const float4*)Wl;
#pragma unroll 4
    for (int k = 0; k < 64; ++k) {
        float4 b = Wlr4[k * 16 + tx];
        float a0 = Xs[(ty * 4 + 0) * 65 + k];
        float a1 = Xs[(ty * 4 + 1) * 65 + k];
        float a2 = Xs[(ty * 4 + 2) * 65 + k];
        float a3 = Xs[(ty * 4 + 3) * 65 + k];
        acc[0][0] += a0 * b.x; acc[0][1] += a0 * b.y; acc[0][2] += a0 * b.z; acc[0][3] += a0 * b.w;
        acc[1][0] += a1 * b.x; acc[1][1] += a1 * b.y; acc[1][2] += a1 * b.z; acc[1][3] += a1 * b.w;
        acc[2][0] += a2 * b.x; acc[2][1] += a2 * b.y; acc[2][2] += a2 * b.z; acc[2][3] += a2 * b.w;
        acc[3][0] += a3 * b.x; acc[3][1] += a3 * b.y; acc[3][2] += a3 * b.z; acc[3][3] += a3 * b.w;
    }
#pragma unroll
    for (int j = 0; j < 4; ++j) {
        int row = row0 + ty * 4 + j;
        if (row < n) {
            float dn = dinv[row];
            __half2 p01 = __float22half2_rn(make_float2(acc[j][0] * dn, acc[j][1] * dn));
            __half2 p23 = __float22half2_rn(make_float2(acc[j][2] * dn, acc[j][3] * dn));
            float2 st;
            st.x = *reinterpret_cast<float*>(&p01);
            st.y = *reinterpret_cast<float*>(&p23);
            H[(size_t)row * 16 + tx] = st;
        }
    }
}

#define UNPACK_ACC(A, RAW) do {                                              \
    __half2 _h01 = *reinterpret_cast<__half2*>(&(RAW).x);                    \
    __half2 _h23 = *reinterpret_cast<__half2*>(&(RAW).y);                    \
    float2 _f01 = __half22float2(_h01);                                      \
    float2 _f23 = __half22float2(_h23);                                      \
    (A).x += _f01.x; (A).y += _f01.y; (A).z += _f23.x; (A).w += _f23.y;      \
} while (0)

// one QUARTER-wave (16 lanes) per node; lane c4 owns channels 4*c4..4*c4+3 (fp16 x4 = 8B).
// Inner edge loop unrolled 8/4/1-wide so up to 8 gathers are in flight per quarter.
__global__ void agg_kernel(const float2* __restrict__ h2, const int* __restrict__ row_ptr,
                           const int* __restrict__ csr_src, const float* __restrict__ dinv,
                           const float* __restrict__ b, const float* __restrict__ xprev,
                           float* __restrict__ xout, float* __restrict__ outp,
                           const float* __restrict__ Wc, const float* __restrict__ bc,
                           int n, int residual, int project) {
    int lane = threadIdx.x & 63;
    int q = lane >> 4, c4 = lane & 15;
    int wid = (blockIdx.x * blockDim.x + threadIdx.x) >> 6;
    int node = wid * 4 + q;
    bool active = node < n;
    int nc = active ? node : 0;
    int beg = row_ptr[nc], end = row_ptr[nc + 1];
    int cnt = end - beg;
    float4 acc = make_float4(0.f, 0.f, 0.f, 0.f);
    {
        float2 raw = h2[(size_t)nc * 16 + c4];  // self loop (pre-scaled by dinv[src])
        UNPACK_ACC(acc, raw);
    }
    int base = q * 16;
    for (int k = 0; k < cnt; k += 16) {
        int p = beg + k + c4;
        int sv = (p < end) ? csr_src[p] : 0;
        int m = min(16, cnt - k);
        int i = 0;
        for (; i + 8 <= m; i += 8) {
            int s0 = __shfl(sv, base + i + 0);
            int s1 = __shfl(sv, base + i + 1);
            int s2 = __shfl(sv, base + i + 2);
            int s3 = __shfl(sv, base + i + 3);
            int s4 = __shfl(sv, base + i + 4);
            int s5 = __shfl(sv, base + i + 5);
            int s6 = __shfl(sv, base + i + 6);
            int s7 = __shfl(sv, base + i + 7);
            float2 v0 = h2[(size_t)s0 * 16 + c4];
            float2 v1 = h2[(size_t)s1 * 16 + c4];
            float2 v2 = h2[(size_t)s2 * 16 + c4];
            float2 v3 = h2[(size_t)s3 * 16 + c4];
            float2 v4 = h2[(size_t)s4 * 16 + c4];
            float2 v5 = h2[(size_t)s5 * 16 + c4];
            float2 v6 = h2[(size_t)s6 * 16 + c4];
            float2 v7 = h2[(size_t)s7 * 16 + c4];
            UNPACK_ACC(acc, v0); UNPACK_ACC(acc, v1); UNPACK_ACC(acc, v2); UNPACK_ACC(acc, v3);
            UNPACK_ACC(acc, v4); UNPACK_ACC(acc, v5); UNPACK_ACC(acc, v6); UNPACK_ACC(acc, v7);
        }
        for (; i + 4 <= m; i += 4) {
            int s0 = __shfl(sv, base + i + 0);
            int s1 = __shfl(sv, base + i + 1);
            int s2 = __shfl(sv, base + i + 2);
            int s3 = __shfl(sv, base + i + 3);
            float2 v0 = h2[(size_t)s0 * 16 + c4];
            float2 v1 = h2[(size_t)s1 * 16 + c4];
            float2 v2 = h2[(size_t)s2 * 16 + c4];
            float2 v3 = h2[(size_t)s3 * 16 + c4];
            UNPACK_ACC(acc, v0); UNPACK_ACC(acc, v1); UNPACK_ACC(acc, v2); UNPACK_ACC(acc, v3);
        }
        for (; i < m; ++i) {
            int s = __shfl(sv, base + i);
            float2 hv = h2[(size_t)s * 16 + c4];
            UNPACK_ACC(acc, hv);
        }
    }
    if (active) {
        float dn = dinv[node];
        float4 bb = ((const float4*)b)[c4];
        float4 v;
        v.x = acc.x * dn + bb.x; v.y = acc.y * dn + bb.y;
        v.z = acc.z * dn + bb.z; v.w = acc.w * dn + bb.w;
        if (residual) {
            float4 r = ((const float4*)xprev)[(size_t)node * 16 + c4];
            v.x += r.x; v.y += r.y; v.z += r.z; v.w += r.w;
        }
        v.x = fmaxf(v.x, 0.f); v.y = fmaxf(v.y, 0.f);
        v.z = fmaxf(v.z, 0.f); v.w = fmaxf(v.w, 0.f);
        if (!project) {
            ((float4*)xout)[(size_t)node * 16 + c4] = v;
        } else {
            int cb = c4 * 4;
#pragma unroll
            for (int j = 0; j < 3; ++j) {
                float p = v.x * Wc[(cb + 0) * 3 + j] + v.y * Wc[(cb + 1) * 3 + j] +
                          v.z * Wc[(cb + 2) * 3 + j] + v.w * Wc[(cb + 3) * 3 + j];
                p += __shfl_down(p, 8);
                p += __shfl_down(p, 4);
                p += __shfl_down(p, 2);
                p += __shfl_down(p, 1);
                if (c4 == 0) outp[node * 3 + j] = p + bc[j];
            }
        }
    }
}

extern "C" void kernel_launch(void* const* d_in, const int* in_sizes, int n_in,
                              void* d_out, int out_size, void* d_ws, size_t ws_size,
                              hipStream_t stream) {
    const float* x  = (const float*)d_in[0];
    const int*   ei = (const int*)d_in[1];
    const float* Ws = (const float*)d_in[2];
    const float* bs = (const float*)d_in[3];
    const float* Wc = (const float*)d_in[4];
    const float* bc = (const float*)d_in[5];
    float* out = (float*)d_out;

    int E = in_sizes[1] / 2;
    const int* src = ei;
    const int* dst = ei + E;
    int nb = (NN + 255) / 256;

    char* wsb = (char*)d_ws;
    size_t off = 0;
    int*   deg     = (int*)(wsb + off); off += 100352 * 4;
    float* dinv    = (float*)(wsb + off); off += 100352 * 4;
    int*   row_ptr = (int*)(wsb + off); off += 100608 * 4;
    int*   bcur    = (int*)(wsb + off); off += 512 * 4;
    int*   bsum    = (int*)(wsb + off); off += 512 * 4;
    int*   csr_src = (int*)(wsb + off); off += ((size_t)E + 256) * 4;
    int2*  ebuf    = (int2*)(wsb + off); off += (size_t)E * 8;           // bucketed pairs
    float2* h      = (float2*)(wsb + off); off += (size_t)NN * HD * 2;   // fp16 h
    float* xa      = (float*)(wsb + off); off += (size_t)NN * HD * 4;
    float* xb      = (float*)(wsb + off); off += (size_t)NN * HD * 4;

    // graph build
    hipMemsetAsync(deg, 0, NN * sizeof(int), stream);
    deg_kernel<<<(E + 255) / 256, 256, 0, stream>>>(dst, deg, E);
    dinv_kernel<<<(NN + 255) / 256, 256, 0, stream>>>(deg, dinv, NN);
    scanA_kernel<<<nb, 256, 0, stream>>>(deg, bsum, NN);
    scanB_kernel<<<1, 512, 0, stream>>>(bsum, row_ptr, nb, NN);
    scanC_kernel<<<nb, 256, 0, stream>>>(deg, bsum, row_ptr, NN);
    bcur_init_kernel<<<(NB + 255) / 256, 256, 0, stream>>>(row_ptr, bcur);
    p1_kernel<<<(E + P1_CHUNK - 1) / P1_CHUNK, 256, 0, stream>>>(src, dst, bcur, ebuf, E);
    p2_kernel<<<NB, 256, 0, stream>>>(ebuf, row_ptr, csr_src, NN);

    // layers (ping-pong xa/xb); layer 3 fuses projection into agg epilogue
    const float* xin = x;
    float* bufs[2] = {xa, xb};
    int agg_blocks = ((NN + 3) / 4 * 64 + 255) / 256;  // 4 nodes per wave
    for (int l = 0; l < 4; ++l) {
        float* xout = bufs[l & 1];
        matmul64_kernel<<<(NN + 63) / 64, 256, 0, stream>>>(
            xin, Ws + (size_t)l * HD * HD, dinv, h, NN);
        agg_kernel<<<agg_blocks, 256, 0, stream>>>(
            h, row_ptr, csr_src, dinv, bs + l * HD, xin, xout,
            out, Wc, bc, NN, l > 0, l == 3);
        xin = xout;
    }
}

// Round 10
// 346.790 us; speedup vs baseline: 2.7347x; 1.1787x over previous
//
#include <hip/hip_runtime.h>
#include <hip/hip_fp16.h>

#define NN 100000
#define HD 64
#define NB ((NN + 255) >> 8)   // 391 dst-buckets of 256 nodes
#define P1_CHUNK 8192

// k1: per-chunk LDS histogram of dst>>8 -> global bucket counts
__global__ __launch_bounds__(256) void hist_kernel(const int* __restrict__ dst,
                                                   int* __restrict__ bcnt, int E) {
    __shared__ int hist[NB];
    int t = threadIdx.x;
    int e0 = blockIdx.x * P1_CHUNK;
    int count = min(P1_CHUNK, E - e0);
    for (int b = t; b < NB; b += 256) hist[b] = 0;
    __syncthreads();
    for (int i = t; i < count; i += 256) atomicAdd(&hist[dst[e0 + i] >> 8], 1);
    __syncthreads();
    for (int b = t; b < NB; b += 256) {
        int c = hist[b];
        if (c) atomicAdd(&bcnt[b], c);
    }
}

// k2: single block scan of NB bucket counts -> boff (exclusive), bcur copy
__global__ void bscan_kernel(const int* __restrict__ bcnt, int* __restrict__ boff,
                             int* __restrict__ bcur, int* __restrict__ row_ptr,
                             int E, int n) {
    __shared__ int sm[512];
    int t = threadIdx.x;
    int v = (t < NB) ? bcnt[t] : 0;
    sm[t] = v;
    __syncthreads();
    for (int off = 1; off < 512; off <<= 1) {
        int u = (t >= off) ? sm[t - off] : 0;
        __syncthreads();
        sm[t] += u;
        __syncthreads();
    }
    if (t < NB) {
        boff[t] = sm[t] - v;
        bcur[t] = sm[t] - v;
    }
    if (t == 0) {
        boff[NB] = E;
        row_ptr[n] = E;
    }
}

// k3: chunked bucket scatter — LDS hist, one global atomic per (block,bucket), LDS cursors
__global__ __launch_bounds__(256) void p1_kernel(const int* __restrict__ src,
                                                 const int* __restrict__ dst,
                                                 int* __restrict__ bcur,
                                                 int2* __restrict__ ebuf, int E) {
    __shared__ int hist[NB];
    __shared__ int cur[NB];
    int t = threadIdx.x;
    int e0 = blockIdx.x * P1_CHUNK;
    int count = min(P1_CHUNK, E - e0);
    for (int b = t; b < NB; b += 256) hist[b] = 0;
    __syncthreads();
    for (int i = t; i < count; i += 256) atomicAdd(&hist[dst[e0 + i] >> 8], 1);
    __syncthreads();
    for (int b = t; b < NB; b += 256) {
        int c = hist[b];
        cur[b] = c ? atomicAdd(&bcur[b], c) : 0;
    }
    __syncthreads();
    for (int i = t; i < count; i += 256) {
        int d = dst[e0 + i], s = src[e0 + i];
        int pos = atomicAdd(&cur[d >> 8], 1);
        ebuf[pos] = make_int2(d, s);
    }
}

// k4: one block per bucket — LDS degree count + scan -> row_ptr/dinv, then local scatter
__global__ __launch_bounds__(256) void p2_kernel(const int2* __restrict__ ebuf,
                                                 const int* __restrict__ boff,
                                                 int* __restrict__ row_ptr,
                                                 float* __restrict__ dinv,
                                                 int* __restrict__ csr_src, int n) {
    __shared__ int cnt[256];
    __shared__ int cur[256];
    int b = blockIdx.x;
    int node0 = b << 8;
    int t = threadIdx.x;
    int beg = boff[b], end = boff[b + 1];
    cnt[t] = 0;
    __syncthreads();
    for (int i = beg + t; i < end; i += 256) atomicAdd(&cnt[ebuf[i].x - node0], 1);
    __syncthreads();
    int deg = cnt[t];
    for (int off = 1; off < 256; off <<= 1) {   // inclusive scan
        int v = (t >= off) ? cnt[t - off] : 0;
        __syncthreads();
        cnt[t] += v;
        __syncthreads();
    }
    int excl = cnt[t] - deg;
    int node = node0 + t;
    if (node < n) {
        row_ptr[node] = beg + excl;
        dinv[node] = rsqrtf((float)deg + 1.0f);   // +1 = self loop
    }
    cur[t] = beg + excl;
    __syncthreads();
    for (int i = beg + t; i < end; i += 256) {
        int2 p = ebuf[i];
        int pos = atomicAdd(&cur[p.x - node0], 1);
        csr_src[pos] = p.y;
    }
}

// H(fp16) = (X @ W) * dinv[row] — 64x64 tile/block, 4x4 micro-tile/thread
__global__ __launch_bounds__(256) void matmul64_kernel(const float* __restrict__ X,
                                                       const float* __restrict__ W,
                                                       const float* __restrict__ dinv,
                                                       float2* __restrict__ H, int n) {
    __shared__ float Wl[64 * 64];      // [k][c], float4-aligned
    __shared__ float Xs[64 * 65];      // [r][k], padded
    int tid = threadIdx.x;
    int row0 = blockIdx.x * 64;
    const float4* W4 = (const float4*)W;
    float4* Wl4 = (float4*)Wl;
#pragma unroll
    for (int i = 0; i < 4; ++i) Wl4[tid + 256 * i] = W4[tid + 256 * i];
#pragma unroll
    for (int i = 0; i < 4; ++i) {
        int l = tid + 256 * i;          // 1024 float4s = 64 rows x 16
        int r = l >> 4, k0 = (l & 15) * 4;
        int row = row0 + r;
        float4 xv = (row < n) ? ((const float4*)X)[(size_t)row * 16 + (l & 15)]
                              : make_float4(0.f, 0.f, 0.f, 0.f);
        Xs[r * 65 + k0 + 0] = xv.x;
        Xs[r * 65 + k0 + 1] = xv.y;
        Xs[r * 65 + k0 + 2] = xv.z;
        Xs[r * 65 + k0 + 3] = xv.w;
    }
    __syncthreads();
    int tx = tid & 15, ty = tid >> 4;   // cols c0=4*tx, rows r0=4*ty
    float acc[4][4] = {};
    const float4* Wlr4 = (const float4*)Wl;
#pragma unroll 4
    for (int k = 0; k < 64; ++k) {
        float4 b = Wlr4[k * 16 + tx];
        float a0 = Xs[(ty * 4 + 0) * 65 + k];
        float a1 = Xs[(ty * 4 + 1) * 65 + k];
        float a2 = Xs[(ty * 4 + 2) * 65 + k];
        float a3 = Xs[(ty * 4 + 3) * 65 + k];
        acc[0][0] += a0 * b.x; acc[0][1] += a0 * b.y; acc[0][2] += a0 * b.z; acc[0][3] += a0 * b.w;
        acc[1][0] += a1 * b.x; acc[1][1] += a1 * b.y; acc[1][2] += a1 * b.z; acc[1][3] += a1 * b.w;
        acc[2][0] += a2 * b.x; acc[2][1] += a2 * b.y; acc[2][2] += a2 * b.z; acc[2][3] += a2 * b.w;
        acc[3][0] += a3 * b.x; acc[3][1] += a3 * b.y; acc[3][2] += a3 * b.z; acc[3][3] += a3 * b.w;
    }
#pragma unroll
    for (int j = 0; j < 4; ++j) {
        int row = row0 + ty * 4 + j;
        if (row < n) {
            float dn = dinv[row];
            __half2 p01 = __float22half2_rn(make_float2(acc[j][0] * dn, acc[j][1] * dn));
            __half2 p23 = __float22half2_rn(make_float2(acc[j][2] * dn, acc[j][3] * dn));
            float2 st;
            st.x = *reinterpret_cast<float*>(&p01);
            st.y = *reinterpret_cast<float*>(&p23);
            H[(size_t)row * 16 + tx] = st;
        }
    }
}

#define UNPACK_ACC(A, RAW) do {                                              \
    __half2 _h01 = *reinterpret_cast<__half2*>(&(RAW).x);                    \
    __half2 _h23 = *reinterpret_cast<__half2*>(&(RAW).y);                    \
    float2 _f01 = __half22float2(_h01);                                      \
    float2 _f23 = __half22float2(_h23);                                      \
    (A).x += _f01.x; (A).y += _f01.y; (A).z += _f23.x; (A).w += _f23.y;      \
} while (0)

// one QUARTER-wave (16 lanes) per node; lane c4 owns channels 4*c4..4*c4+3 (fp16 x4 = 8B).
// Inner edge loop unrolled 8/4/1-wide so up to 8 gathers are in flight per quarter.
__global__ void agg_kernel(const float2* __restrict__ h2, const int* __restrict__ row_ptr,
                           const int* __restrict__ csr_src, const float* __restrict__ dinv,
                           const float* __restrict__ b, const float* __restrict__ xprev,
                           float* __restrict__ xout, float* __restrict__ outp,
                           const float* __restrict__ Wc, const float* __restrict__ bc,
                           int n, int residual, int project) {
    int lane = threadIdx.x & 63;
    int q = lane >> 4, c4 = lane & 15;
    int wid = (blockIdx.x * blockDim.x + threadIdx.x) >> 6;
    int node = wid * 4 + q;
    bool active = node < n;
    int nc = active ? node : 0;
    int beg = row_ptr[nc], end = row_ptr[nc + 1];
    int cnt = end - beg;
    float4 acc = make_float4(0.f, 0.f, 0.f, 0.f);
    {
        float2 raw = h2[(size_t)nc * 16 + c4];  // self loop (pre-scaled by dinv[src])
        UNPACK_ACC(acc, raw);
    }
    int base = q * 16;
    for (int k = 0; k < cnt; k += 16) {
        int p = beg + k + c4;
        int sv = (p < end) ? csr_src[p] : 0;
        int m = min(16, cnt - k);
        int i = 0;
        for (; i + 8 <= m; i += 8) {
            int s0 = __shfl(sv, base + i + 0);
            int s1 = __shfl(sv, base + i + 1);
            int s2 = __shfl(sv, base + i + 2);
            int s3 = __shfl(sv, base + i + 3);
            int s4 = __shfl(sv, base + i + 4);
            int s5 = __shfl(sv, base + i + 5);
            int s6 = __shfl(sv, base + i + 6);
            int s7 = __shfl(sv, base + i + 7);
            float2 v0 = h2[(size_t)s0 * 16 + c4];
            float2 v1 = h2[(size_t)s1 * 16 + c4];
            float2 v2 = h2[(size_t)s2 * 16 + c4];
            float2 v3 = h2[(size_t)s3 * 16 + c4];
            float2 v4 = h2[(size_t)s4 * 16 + c4];
            float2 v5 = h2[(size_t)s5 * 16 + c4];
            float2 v6 = h2[(size_t)s6 * 16 + c4];
            float2 v7 = h2[(size_t)s7 * 16 + c4];
            UNPACK_ACC(acc, v0); UNPACK_ACC(acc, v1); UNPACK_ACC(acc, v2); UNPACK_ACC(acc, v3);
            UNPACK_ACC(acc, v4); UNPACK_ACC(acc, v5); UNPACK_ACC(acc, v6); UNPACK_ACC(acc, v7);
        }
        for (; i + 4 <= m; i += 4) {
            int s0 = __shfl(sv, base + i + 0);
            int s1 = __shfl(sv, base + i + 1);
            int s2 = __shfl(sv, base + i + 2);
            int s3 = __shfl(sv, base + i + 3);
            float2 v0 = h2[(size_t)s0 * 16 + c4];
            float2 v1 = h2[(size_t)s1 * 16 + c4];
            float2 v2 = h2[(size_t)s2 * 16 + c4];
            float2 v3 = h2[(size_t)s3 * 16 + c4];
            UNPACK_ACC(acc, v0); UNPACK_ACC(acc, v1); UNPACK_ACC(acc, v2); UNPACK_ACC(acc, v3);
        }
        for (; i < m; ++i) {
            int s = __shfl(sv, base + i);
            float2 hv = h2[(size_t)s * 16 + c4];
            UNPACK_ACC(acc, hv);
        }
    }
    if (active) {
        float dn = dinv[node];
        float4 bb = ((const float4*)b)[c4];
        float4 v;
        v.x = acc.x * dn + bb.x; v.y = acc.y * dn + bb.y;
        v.z = acc.z * dn + bb.z; v.w = acc.w * dn + bb.w;
        if (residual) {
            float4 r = ((const float4*)xprev)[(size_t)node * 16 + c4];
            v.x += r.x; v.y += r.y; v.z += r.z; v.w += r.w;
        }
        v.x = fmaxf(v.x, 0.f); v.y = fmaxf(v.y, 0.f);
        v.z = fmaxf(v.z, 0.f); v.w = fmaxf(v.w, 0.f);
        if (!project) {
            ((float4*)xout)[(size_t)node * 16 + c4] = v;
        } else {
            int cb = c4 * 4;
#pragma unroll
            for (int j = 0; j < 3; ++j) {
                float p = v.x * Wc[(cb + 0) * 3 + j] + v.y * Wc[(cb + 1) * 3 + j] +
                          v.z * Wc[(cb + 2) * 3 + j] + v.w * Wc[(cb + 3) * 3 + j];
                p += __shfl_down(p, 8);
                p += __shfl_down(p, 4);
                p += __shfl_down(p, 2);
                p += __shfl_down(p, 1);
                if (c4 == 0) outp[node * 3 + j] = p + bc[j];
            }
        }
    }
}

extern "C" void kernel_launch(void* const* d_in, const int* in_sizes, int n_in,
                              void* d_out, int out_size, void* d_ws, size_t ws_size,
                              hipStream_t stream) {
    const float* x  = (const float*)d_in[0];
    const int*   ei = (const int*)d_in[1];
    const float* Ws = (const float*)d_in[2];
    const float* bs = (const float*)d_in[3];
    const float* Wc = (const float*)d_in[4];
    const float* bc = (const float*)d_in[5];
    float* out = (float*)d_out;

    int E = in_sizes[1] / 2;
    const int* src = ei;
    const int* dst = ei + E;
    int nchunks = (E + P1_CHUNK - 1) / P1_CHUNK;

    char* wsb = (char*)d_ws;
    size_t off = 0;
    int*   bcnt    = (int*)(wsb + off); off += 512 * 4;
    int*   boff    = (int*)(wsb + off); off += 512 * 4;
    int*   bcur    = (int*)(wsb + off); off += 512 * 4;
    int*   row_ptr = (int*)(wsb + off); off += 100608 * 4;
    float* dinv    = (float*)(wsb + off); off += 100352 * 4;
    int*   csr_src = (int*)(wsb + off); off += ((size_t)E + 256) * 4;
    int2*  ebuf    = (int2*)(wsb + off); off += (size_t)E * 8;           // bucketed pairs
    float2* h      = (float2*)(wsb + off); off += (size_t)NN * HD * 2;   // fp16 h
    float* xa      = (float*)(wsb + off); off += (size_t)NN * HD * 4;
    float* xb      = (float*)(wsb + off); off += (size_t)NN * HD * 4;

    // graph build: bucket counts -> offsets -> bucketed pairs -> per-bucket CSR+deg+dinv
    hipMemsetAsync(bcnt, 0, 512 * sizeof(int), stream);
    hist_kernel<<<nchunks, 256, 0, stream>>>(dst, bcnt, E);
    bscan_kernel<<<1, 512, 0, stream>>>(bcnt, boff, bcur, row_ptr, E, NN);
    p1_kernel<<<nchunks, 256, 0, stream>>>(src, dst, bcur, ebuf, E);
    p2_kernel<<<NB, 256, 0, stream>>>(ebuf, boff, row_ptr, dinv, csr_src, NN);

    // layers (ping-pong xa/xb); layer 3 fuses projection into agg epilogue
    const float* xin = x;
    float* bufs[2] = {xa, xb};
    int agg_blocks = ((NN + 3) / 4 * 64 + 255) / 256;  // 4 nodes per wave
    for (int l = 0; l < 4; ++l) {
        float* xout = bufs[l & 1];
        matmul64_kernel<<<(NN + 63) / 64, 256, 0, stream>>>(
            xin, Ws + (size_t)l * HD * HD, dinv, h, NN);
        agg_kernel<<<agg_blocks, 256, 0, stream>>>(
            h, row_ptr, csr_src, dinv, bs + l * HD, xin, xout,
            out, Wc, bc, NN, l > 0, l == 3);
        xin = xout;
    }
}